// Round 5
// baseline (121.807 us; speedup 1.0000x reference)
//
#include <hip/hip_runtime.h>
#include <hip/hip_bf16.h>

#define NPIX 9216
#define SPLIT 8
#define NSEG (NPIX / SPLIT)   // 1152 n per block
#define NT (NSEG / 32)        // 36 tiles
#define MTILES (NPIX / 16)    // 576

typedef __attribute__((ext_vector_type(4))) float f32x4;
typedef __attribute__((ext_vector_type(8))) short bf16x8;
typedef __attribute__((ext_vector_type(2))) unsigned int u32x2;

// ---------------- Kernel 1: spectral norm sigmas (1 block, 64 threads) ------
__global__ void spectral_kernel(const float* __restrict__ Wf, const float* __restrict__ Wg,
                                const float* __restrict__ Wh, const float* __restrict__ uf,
                                const float* __restrict__ ug, const float* __restrict__ uh,
                                float* __restrict__ inv_sigma) {
  __shared__ float vsh[64];
  const int t = threadIdx.x;
  for (int widx = 0; widx < 3; ++widx) {
    const float* W = (widx == 0) ? Wf : (widx == 1) ? Wg : Wh;
    const float* u = (widx == 0) ? uf : (widx == 1) ? ug : uh;
    const int O = (widx == 2) ? 64 : 8;
    float v = 0.f;
    for (int o = 0; o < O; ++o) v += W[o * 64 + t] * u[o];
    float s = v * v;
    for (int off = 32; off; off >>= 1) s += __shfl_xor(s, off);
    const float vn = v / (sqrtf(s) + 1e-12f);
    vsh[t] = vn;
    __syncthreads();
    float wv = 0.f;
    if (t < O) { for (int c = 0; c < 64; ++c) wv += W[t * 64 + c] * vsh[c]; }
    float s2 = (t < O) ? wv * wv : 0.f;
    for (int off = 32; off; off >>= 1) s2 += __shfl_xor(s2, off);
    const float nw = sqrtf(s2);
    const float sigma = s2 / (nw + 1e-12f);
    if (t == 0) inv_sigma[widx] = 1.f / sigma;
    __syncthreads();
  }
}

// ---------------- Kernel 2: f,g,h projections --------------------------------
// Qp  : [NPIX][16] bf16  (qh[0..7], ql[0..7]) of (f * 0.25)  [hi/lo split]
// Kp  : [NPIX][16] bf16  (kh[0..7], kl[0..7]) of g           [hi/lo split]
// Vt2 : [288 tiles][64 c][4 g][2 t][4 i] bf16 — tile-contiguous 4KB; pixel
//       n -> tile=n>>5, within-tile offset n&31 = 16t+4g+i; element (c,n) at
//       ushort idx tile*2048 + c*32 + g*8 + t*4 + i.  One b128 per (lane,ct)
//       in the attention PV gather.
__global__ __launch_bounds__(256) void fgh_kernel(
    const float* __restrict__ x,
    const float* __restrict__ Wf, const float* __restrict__ bfv,
    const float* __restrict__ Wg, const float* __restrict__ bgv,
    const float* __restrict__ Wh, const float* __restrict__ bhv,
    const float* __restrict__ inv_sigma,
    ushort* __restrict__ Qp, ushort* __restrict__ Kp, ushort* __restrict__ Vt2) {
  const int p = blockIdx.x * 256 + threadIdx.x;
  const int by = blockIdx.y;
  float xv[64];
  #pragma unroll
  for (int c = 0; c < 64; ++c) xv[c] = x[c * NPIX + p];

  if (by == 0) {
    const float isf = inv_sigma[0], isg = inv_sigma[1];
    for (int r = 0; r < 8; ++r) {
      float a = 0.f;
      #pragma unroll
      for (int c = 0; c < 64; ++c) a += Wf[r * 64 + c] * xv[c];
      const float vq = (a * isf + bfv[r]) * 0.25f;  // folds K-broadcast /4
      const __hip_bfloat16 h = __float2bfloat16(vq);
      const float hf = __bfloat162float(h);
      const __hip_bfloat16 lo = __float2bfloat16(vq - hf);
      Qp[p * 16 + r]     = *(const ushort*)&h;
      Qp[p * 16 + 8 + r] = *(const ushort*)&lo;
    }
    for (int r = 0; r < 8; ++r) {
      float a = 0.f;
      #pragma unroll
      for (int c = 0; c < 64; ++c) a += Wg[r * 64 + c] * xv[c];
      const float val = a * isg + bgv[r];
      const __hip_bfloat16 h = __float2bfloat16(val);
      const float hf = __bfloat162float(h);
      const __hip_bfloat16 lo = __float2bfloat16(val - hf);
      Kp[p * 16 + r]     = *(const ushort*)&h;
      Kp[p * 16 + 8 + r] = *(const ushort*)&lo;
    }
  } else {
    const float ish = inv_sigma[2];
    const int tile = p >> 5;
    const int nr = p & 31;                       // = 16t + 4g + i
    const int tt = nr >> 4, gg = (nr >> 2) & 3, ii = nr & 3;
    ushort* vout = Vt2 + (size_t)tile * 2048 + gg * 8 + tt * 4 + ii;
    const int rbase = (by - 1) * 16;
    for (int rr = 0; rr < 16; ++rr) {
      const int r = rbase + rr;
      float a = 0.f;
      #pragma unroll
      for (int c = 0; c < 64; ++c) a += Wh[r * 64 + c] * xv[c];
      const float val = a * ish + bhv[r];
      const __hip_bfloat16 hv = __float2bfloat16(val);
      vout[r * 32] = *(const ushort*)&hv;       // c-stride = 32 ushorts
    }
  }
}

// ---------------- Kernel 3a: flash attention, register-direct, no barriers ---
// Grid (144, SPLIT). Block = 64 m-rows; wave w owns m-rows bx*64+w*16..+15.
// All 4 waves walk the same n-range -> K/V global reads hit L1 after the
// first wave. No LDS, no __syncthreads in the loop. K regs double-buffered;
// V issued at loop top (covered by QK+softmax). Defer-max: common path has
// NO cross-lane reduction (lane-local max feeds __any); ls kept lane-partial,
// reduced across g once at the end.
__global__ __launch_bounds__(256) void attn_kernel(
    const ushort* __restrict__ Qp, const ushort* __restrict__ Kp,
    const ushort* __restrict__ Vt2,
    ushort* __restrict__ Om,   // [576 mt][SPLIT][1024] bf16 (e = c*16 + m)
    float* __restrict__ Sm) {  // [576 mt][SPLIT][32]  f32 (16 mx, 16 ls)
  const int tid  = threadIdx.x;
  const int w    = tid >> 6;
  const int l    = tid & 63;
  const int mloc = l & 15;
  const int g    = l >> 4;
  const int spl  = blockIdx.y;
  const int mrow = blockIdx.x * 64 + w * 16 + mloc;

  const bf16x8 qh = *(const bf16x8*)(Qp + mrow * 16);
  const bf16x8 ql = *(const bf16x8*)(Qp + mrow * 16 + 8);

  const int n0 = spl * NSEG;
  const ushort* kb = Kp + (size_t)(n0 + mloc) * 16;
  const ushort* vb = Vt2 + (size_t)(n0 >> 5) * 2048 + mloc * 32 + g * 8;

  // K tile 0 (double-buffered across iterations)
  bf16x8 kh0 = *(const bf16x8*)(kb);
  bf16x8 kl0 = *(const bf16x8*)(kb + 8);
  bf16x8 kh1 = *(const bf16x8*)(kb + 256);
  bf16x8 kl1 = *(const bf16x8*)(kb + 264);

  float mx = -INFINITY, ls = 0.f;
  const f32x4 zero = {0.f, 0.f, 0.f, 0.f};
  f32x4 acc0 = zero, acc1 = zero, acc2 = zero, acc3 = zero;

  for (int t = 0; t < NT; ++t) {
    // ---- V for tile t: issue early, first used after softmax ----
    const ushort* vt = vb + (size_t)t * 2048;
    const bf16x8 v0 = *(const bf16x8*)(vt);           // c = mloc
    const bf16x8 v1 = *(const bf16x8*)(vt + 512);     // c = 16 + mloc
    const bf16x8 v2 = *(const bf16x8*)(vt + 1024);    // c = 32 + mloc
    const bf16x8 v3 = *(const bf16x8*)(vt + 1536);    // c = 48 + mloc

    // ---- S^T = K . Q^T (2 n-subtiles x 3 hi/lo MFMAs) ----
    f32x4 s0 = zero, s1 = zero;
    s0 = __builtin_amdgcn_mfma_f32_16x16x32_bf16(kh0, qh, s0, 0, 0, 0);
    s1 = __builtin_amdgcn_mfma_f32_16x16x32_bf16(kh1, qh, s1, 0, 0, 0);
    s0 = __builtin_amdgcn_mfma_f32_16x16x32_bf16(kh0, ql, s0, 0, 0, 0);
    s1 = __builtin_amdgcn_mfma_f32_16x16x32_bf16(kh1, ql, s1, 0, 0, 0);
    s0 = __builtin_amdgcn_mfma_f32_16x16x32_bf16(kl0, qh, s0, 0, 0, 0);
    s1 = __builtin_amdgcn_mfma_f32_16x16x32_bf16(kl1, qh, s1, 0, 0, 0);

    // ---- prefetch K tile t+1 (loads retire during softmax below) ----
    if (t + 1 < NT) {
      const ushort* kn = kb + (size_t)(t + 1) * 512;
      kh0 = *(const bf16x8*)(kn);
      kl0 = *(const bf16x8*)(kn + 8);
      kh1 = *(const bf16x8*)(kn + 256);
      kl1 = *(const bf16x8*)(kn + 264);
    }

    // ---- online softmax, common path has zero cross-lane ops ----
    const float tm = fmaxf(
        fmaxf(fmaxf(s0[0], s0[1]), fmaxf(s0[2], s0[3])),
        fmaxf(fmaxf(s1[0], s1[1]), fmaxf(s1[2], s1[3])));
    if (__any(tm > mx + 8.0f)) {   // rare (first tile + big jumps only)
      float tr = fmaxf(tm, __shfl_xor(tm, 16));
      tr = fmaxf(tr, __shfl_xor(tr, 32));
      const float mxn = fmaxf(mx, tr);
      const float corr = __expf(mx - mxn);
      ls *= corr;
      const float c0 = __shfl(corr, (g << 2) + 0);
      const float c1 = __shfl(corr, (g << 2) + 1);
      const float c2 = __shfl(corr, (g << 2) + 2);
      const float c3 = __shfl(corr, (g << 2) + 3);
      acc0[0] *= c0; acc0[1] *= c1; acc0[2] *= c2; acc0[3] *= c3;
      acc1[0] *= c0; acc1[1] *= c1; acc1[2] *= c2; acc1[3] *= c3;
      acc2[0] *= c0; acc2[1] *= c1; acc2[2] *= c2; acc2[3] *= c3;
      acc3[0] *= c0; acc3[1] *= c1; acc3[2] *= c2; acc3[3] *= c3;
      mx = mxn;
    }
    float pj[8];
    pj[0] = __expf(s0[0] - mx); pj[1] = __expf(s0[1] - mx);
    pj[2] = __expf(s0[2] - mx); pj[3] = __expf(s0[3] - mx);
    pj[4] = __expf(s1[0] - mx); pj[5] = __expf(s1[1] - mx);
    pj[6] = __expf(s1[2] - mx); pj[7] = __expf(s1[3] - mx);
    ls += ((pj[0] + pj[1]) + (pj[2] + pj[3])) + ((pj[4] + pj[5]) + (pj[6] + pj[7]));

    union { unsigned int u[4]; bf16x8 v; } pu;
    #pragma unroll
    for (int jj = 0; jj < 4; ++jj) {
      unsigned int r;
      asm("v_cvt_pk_bf16_f32 %0, %1, %2" : "=v"(r) : "v"(pj[2 * jj]), "v"(pj[2 * jj + 1]));
      pu.u[jj] = r;
    }
    // ---- PV ----
    acc0 = __builtin_amdgcn_mfma_f32_16x16x32_bf16(pu.v, v0, acc0, 0, 0, 0);
    acc1 = __builtin_amdgcn_mfma_f32_16x16x32_bf16(pu.v, v1, acc1, 0, 0, 0);
    acc2 = __builtin_amdgcn_mfma_f32_16x16x32_bf16(pu.v, v2, acc2, 0, 0, 0);
    acc3 = __builtin_amdgcn_mfma_f32_16x16x32_bf16(pu.v, v3, acc3, 0, 0, 0);
  }

  // ---- finalize: ls row-total across g, write un-normalized partials ----
  ls += __shfl_xor(ls, 16);
  ls += __shfl_xor(ls, 32);

  const size_t mt = (size_t)blockIdx.x * 4 + w;
  ushort* Ob = Om + (mt * SPLIT + spl) * 1024;
  float*  Sb = Sm + (mt * SPLIT + spl) * 32;
  #pragma unroll
  for (int ct = 0; ct < 4; ++ct) {
    const f32x4 a = (ct == 0) ? acc0 : (ct == 1) ? acc1 : (ct == 2) ? acc2 : acc3;
    unsigned int r0, r1;
    asm("v_cvt_pk_bf16_f32 %0, %1, %2" : "=v"(r0) : "v"(a[0]), "v"(a[1]));
    asm("v_cvt_pk_bf16_f32 %0, %1, %2" : "=v"(r1) : "v"(a[2]), "v"(a[3]));
    u32x2 pk; pk[0] = r0; pk[1] = r1;
    *(u32x2*)(Ob + (ct * 16 + mloc) * 16 + 4 * g) = pk;  // e = c*16 + (4g+i)
  }
  if (l < 16) { Sb[l] = mx; Sb[16 + l] = ls; }
}

// ---------------- Kernel 3b: combine split partials --------------------------
__global__ __launch_bounds__(256) void combine_kernel(
    const ushort* __restrict__ Om, const float* __restrict__ Sm,
    const float* __restrict__ x, const float* __restrict__ gammap,
    float* __restrict__ out) {
  const int mt = blockIdx.x;
  const int m0 = mt * 16;
  const float gamma = gammap[0];
  const float* Sb = Sm + (size_t)mt * SPLIT * 32;
  const ushort* Ob = Om + (size_t)mt * SPLIT * 1024;
  for (int e = threadIdx.x; e < 1024; e += 256) {
    const int m = e & 15, c = e >> 4;
    float M = -INFINITY;
    #pragma unroll
    for (int s = 0; s < SPLIT; ++s) M = fmaxf(M, Sb[s * 32 + m]);
    float L = 0.f, val = 0.f;
    #pragma unroll
    for (int s = 0; s < SPLIT; ++s) {
      const float wgt = __expf(Sb[s * 32 + m] - M);
      L += Sb[s * 32 + 16 + m] * wgt;
      union { unsigned int i; float f; } cv;
      cv.i = ((unsigned int)Ob[s * 1024 + e]) << 16;
      val += cv.f * wgt;
    }
    const int idx = c * NPIX + m0 + m;
    out[idx] = gamma * (val / L) + x[idx];
  }
}

// ---------------- launcher ---------------------------------------------------
extern "C" void kernel_launch(void* const* d_in, const int* in_sizes, int n_in,
                              void* d_out, int out_size, void* d_ws, size_t ws_size,
                              hipStream_t stream) {
  const float* x     = (const float*)d_in[0];
  const float* Wf    = (const float*)d_in[1];
  const float* bf    = (const float*)d_in[2];
  const float* Wg    = (const float*)d_in[3];
  const float* bg    = (const float*)d_in[4];
  const float* Wh    = (const float*)d_in[5];
  const float* bh    = (const float*)d_in[6];
  const float* gamma = (const float*)d_in[7];
  const float* uf    = (const float*)d_in[8];
  const float* ug    = (const float*)d_in[9];
  const float* uh    = (const float*)d_in[10];
  float* out = (float*)d_out;

  char* ws = (char*)d_ws;
  float*  inv_sigma = (float*)ws;                                    // 12 B
  ushort* Qp  = (ushort*)(ws + 256);                                 // 294912 B
  ushort* Kp  = (ushort*)(ws + 256 + NPIX * 16 * 2);                 // 294912 B
  ushort* Vt2 = (ushort*)(ws + 256 + 2 * NPIX * 16 * 2);             // 1179648 B
  size_t off = 256 + (size_t)2 * NPIX * 16 * 2 + (size_t)NPIX * 64 * 2;
  ushort* Om = (ushort*)(ws + off);                                  // 9437184 B
  float*  Sm = (float*)(ws + off + (size_t)MTILES * SPLIT * 1024 * 2); // 589824 B

  spectral_kernel<<<1, 64, 0, stream>>>(Wf, Wg, Wh, uf, ug, uh, inv_sigma);
  fgh_kernel<<<dim3(NPIX / 256, 5), 256, 0, stream>>>(x, Wf, bf, Wg, bg, Wh, bh,
                                                      inv_sigma, Qp, Kp, Vt2);
  attn_kernel<<<dim3(NPIX / 64, SPLIT), 256, 0, stream>>>(Qp, Kp, Vt2, Om, Sm);
  combine_kernel<<<MTILES, 256, 0, stream>>>(Om, Sm, x, gamma, out);
}

// Round 6
// 83.546 us; speedup vs baseline: 1.4580x; 1.4580x over previous
//
#include <hip/hip_runtime.h>
#include <hip/hip_bf16.h>

#define NPIX 9216
#define SPLIT 8
#define NSEG (NPIX / SPLIT)   // 1152 n per block
#define NT (NSEG / 32)        // 36 tiles
#define MTILES (NPIX / 16)    // 576

typedef __attribute__((ext_vector_type(4))) float f32x4;
typedef __attribute__((ext_vector_type(8))) short bf16x8;
typedef __attribute__((ext_vector_type(2))) unsigned int u32x2;

__device__ __forceinline__ void gload_lds16(const void* g, void* l) {
  __builtin_amdgcn_global_load_lds(
      (const __attribute__((address_space(1))) unsigned int*)g,
      (__attribute__((address_space(3))) unsigned int*)l, 16, 0, 0);
}
__device__ __forceinline__ void gload_lds4(const void* g, void* l) {
  __builtin_amdgcn_global_load_lds(
      (const __attribute__((address_space(1))) unsigned int*)g,
      (__attribute__((address_space(3))) unsigned int*)l, 4, 0, 0);
}
#define LDS_OFF(p) ((unsigned)(unsigned long long)(const __attribute__((address_space(3))) char*)(const char*)(p))

// ---------------- Kernel 1: f,g,h projections (+fused spectral norm) --------
// Qp  : [NPIX][16] bf16  (qh[0..7], ql[0..7]) of (f * 0.25)  [hi/lo split]
// Kp  : [NPIX][16] bf16  (kh[0..7], kl[0..7]) of g           [hi/lo split]
// Vt2 : [288 tiles][64 c][4 g][2 t][4 i] bf16 — tile-contiguous 4KB; pixel
//       n -> tile=n>>5, within-tile n&31 = 16t+4g+i; element (c,n) at
//       ushort idx tile*2048 + c*32 + g*8 + t*4 + i.
__global__ __launch_bounds__(256) void fgh_kernel(
    const float* __restrict__ x,
    const float* __restrict__ Wf, const float* __restrict__ bfv,
    const float* __restrict__ Wg, const float* __restrict__ bgv,
    const float* __restrict__ Wh, const float* __restrict__ bhv,
    const float* __restrict__ uf, const float* __restrict__ ug,
    const float* __restrict__ uh,
    ushort* __restrict__ Qp, ushort* __restrict__ Kp, ushort* __restrict__ Vt2) {
  __shared__ float vsh[64];
  __shared__ float is_s[3];
  const int tid = threadIdx.x;
  if (tid < 64) {  // one wave recomputes spectral sigmas (redundant per block, cheap)
    const int t = tid;
    for (int widx = 0; widx < 3; ++widx) {
      const float* W = (widx == 0) ? Wf : (widx == 1) ? Wg : Wh;
      const float* u = (widx == 0) ? uf : (widx == 1) ? ug : uh;
      const int O = (widx == 2) ? 64 : 8;
      float v = 0.f;
      for (int o = 0; o < O; ++o) v += W[o * 64 + t] * u[o];
      float s = v * v;
      for (int off = 32; off; off >>= 1) s += __shfl_xor(s, off);
      vsh[t] = v / (sqrtf(s) + 1e-12f);   // wave-lockstep: no barrier needed
      float wv = 0.f;
      if (t < O) { for (int c = 0; c < 64; ++c) wv += W[t * 64 + c] * vsh[c]; }
      float s2 = (t < O) ? wv * wv : 0.f;
      for (int off = 32; off; off >>= 1) s2 += __shfl_xor(s2, off);
      const float nw = sqrtf(s2);
      if (t == 0) is_s[widx] = (nw + 1e-12f) / s2;  // 1/sigma
    }
  }
  __syncthreads();

  const int p = blockIdx.x * 256 + tid;
  const int by = blockIdx.y;
  float xv[64];
  #pragma unroll
  for (int c = 0; c < 64; ++c) xv[c] = x[c * NPIX + p];

  if (by == 0) {
    const float isf = is_s[0], isg = is_s[1];
    for (int r = 0; r < 8; ++r) {
      float a = 0.f;
      #pragma unroll
      for (int c = 0; c < 64; ++c) a += Wf[r * 64 + c] * xv[c];
      const float vq = (a * isf + bfv[r]) * 0.25f;  // folds K-broadcast /4
      const __hip_bfloat16 h = __float2bfloat16(vq);
      const float hf = __bfloat162float(h);
      const __hip_bfloat16 lo = __float2bfloat16(vq - hf);
      Qp[p * 16 + r]     = *(const ushort*)&h;
      Qp[p * 16 + 8 + r] = *(const ushort*)&lo;
    }
    for (int r = 0; r < 8; ++r) {
      float a = 0.f;
      #pragma unroll
      for (int c = 0; c < 64; ++c) a += Wg[r * 64 + c] * xv[c];
      const float val = a * isg + bgv[r];
      const __hip_bfloat16 h = __float2bfloat16(val);
      const float hf = __bfloat162float(h);
      const __hip_bfloat16 lo = __float2bfloat16(val - hf);
      Kp[p * 16 + r]     = *(const ushort*)&h;
      Kp[p * 16 + 8 + r] = *(const ushort*)&lo;
    }
  } else {
    const float ish = is_s[2];
    const int tile = p >> 5;
    const int nr = p & 31;                       // = 16t + 4g + i
    const int tt = nr >> 4, gg = (nr >> 2) & 3, ii = nr & 3;
    ushort* vout = Vt2 + (size_t)tile * 2048 + gg * 8 + tt * 4 + ii;
    const int rbase = (by - 1) * 16;
    for (int rr = 0; rr < 16; ++rr) {
      const int r = rbase + rr;
      float a = 0.f;
      #pragma unroll
      for (int c = 0; c < 64; ++c) a += Wh[r * 64 + c] * xv[c];
      const float val = a * ish + bhv[r];
      const __hip_bfloat16 hv = __float2bfloat16(val);
      vout[r * 32] = *(const ushort*)&hv;       // c-stride = 32 ushorts
    }
  }
}

// ---------------- Kernel 2: flash attention, counted-vmcnt pipeline ---------
// Grid (144, SPLIT). Block = 64 m-rows; wave w owns m-rows bx*64+w*16..+15.
// All 4 waves walk the same n-range, convoyed by one raw s_barrier per tile.
// 4 LDS buffers (V 4KB + K 1KB each), prefetch depth 2 via global_load_lds
// (2 vmem/tile/wave uniform), s_waitcnt vmcnt(4) -- never 0 in steady state.
// K/V LDS reads via inline-asm ds_read_b128 + manual lgkmcnt(0)+sched_barrier
// (hides DMA->ds_read alias from compiler; rule #18).
__global__ __launch_bounds__(256) void attn_kernel(
    const ushort* __restrict__ Qp, const ushort* __restrict__ Kp,
    const ushort* __restrict__ Vt2,
    ushort* __restrict__ Om,   // [576 mt][SPLIT][1024] bf16 (e = c*16 + m)
    float* __restrict__ Sm) {  // [576 mt][SPLIT][32]  f32 (16 mx, 16 ls)
  __shared__ ushort Vs[4][2048];  // 4 x 4KB
  __shared__ ushort Ks[4][512];   // 4 x 1KB : [n 0..31][16] (kh8, kl8)
  const int tid  = threadIdx.x;
  const int w    = tid >> 6;
  const int l    = tid & 63;
  const int mloc = l & 15;
  const int g    = l >> 4;
  const int spl  = blockIdx.y;
  const int mrow = blockIdx.x * 64 + w * 16 + mloc;

  bf16x8 qh = *(const bf16x8*)(Qp + mrow * 16);
  bf16x8 ql = *(const bf16x8*)(Qp + mrow * 16 + 8);
  // force Q materialized (compiler emits its vmcnt here, before the loop)
  asm volatile("" : "+v"(qh), "+v"(ql));

  const int n0 = spl * NSEG;
  const char* vsrc = (const char*)Vt2 + ((size_t)(n0 >> 5)) * 4096 + w * 1024 + l * 16;
  const char* ksrc = (const char*)Kp + (size_t)n0 * 32 + w * 256 + l * 4;

  #define STAGE(t_) do {                                                  \
    const int b_ = (t_) & 3;                                              \
    gload_lds16(vsrc + (size_t)(t_) * 4096, (char*)&Vs[b_][0] + w * 1024);\
    gload_lds4 (ksrc + (size_t)(t_) * 1024, (char*)&Ks[b_][0] + w * 256); \
  } while (0)

  STAGE(0);
  STAGE(1);

  const unsigned ks_base = LDS_OFF(&Ks[0][0]);
  const unsigned vs_base = LDS_OFF(&Vs[0][0]);

  float mx = -INFINITY, ls = 0.f;
  const f32x4 zero = {0.f, 0.f, 0.f, 0.f};
  f32x4 acc0 = zero, acc1 = zero, acc2 = zero, acc3 = zero;

  for (int t = 0; t < NT; ++t) {
    const int b = t & 3;
    if (t + 2 < NT) {
      STAGE(t + 2);
      asm volatile("s_waitcnt vmcnt(4)" ::: "memory");  // tile t done; t+1,t+2 in flight
    } else if (t + 1 < NT) {
      asm volatile("s_waitcnt vmcnt(2)" ::: "memory");
    } else {
      asm volatile("s_waitcnt vmcnt(0)" ::: "memory");
    }
    __builtin_amdgcn_s_barrier();   // raw barrier: no compiler vmcnt(0) drain

    // ---- LDS reads (asm: opaque to compiler's LDS-DMA alias tracking) ----
    const unsigned kaddr = ks_base + b * 1024 + mloc * 32;
    const unsigned vaddr = vs_base + b * 4096 + mloc * 64 + g * 16;
    bf16x8 kh0, kl0, kh1, kl1, v0, v1, v2, v3;
    asm volatile("ds_read_b128 %0, %1"            : "=v"(kh0) : "v"(kaddr));
    asm volatile("ds_read_b128 %0, %1 offset:16"  : "=v"(kl0) : "v"(kaddr));
    asm volatile("ds_read_b128 %0, %1 offset:512" : "=v"(kh1) : "v"(kaddr));
    asm volatile("ds_read_b128 %0, %1 offset:528" : "=v"(kl1) : "v"(kaddr));
    asm volatile("ds_read_b128 %0, %1"            : "=v"(v0)  : "v"(vaddr));
    asm volatile("ds_read_b128 %0, %1 offset:1024": "=v"(v1)  : "v"(vaddr));
    asm volatile("ds_read_b128 %0, %1 offset:2048": "=v"(v2)  : "v"(vaddr));
    asm volatile("ds_read_b128 %0, %1 offset:3072": "=v"(v3)  : "v"(vaddr));
    asm volatile("s_waitcnt lgkmcnt(0)" ::: "memory");
    __builtin_amdgcn_sched_barrier(0);  // rule #18: pin MFMA below the wait

    // ---- S^T = K . Q^T (2 n-subtiles x 3 hi/lo MFMAs) ----
    f32x4 s0 = zero, s1 = zero;
    s0 = __builtin_amdgcn_mfma_f32_16x16x32_bf16(kh0, qh, s0, 0, 0, 0);
    s1 = __builtin_amdgcn_mfma_f32_16x16x32_bf16(kh1, qh, s1, 0, 0, 0);
    s0 = __builtin_amdgcn_mfma_f32_16x16x32_bf16(kh0, ql, s0, 0, 0, 0);
    s1 = __builtin_amdgcn_mfma_f32_16x16x32_bf16(kh1, ql, s1, 0, 0, 0);
    s0 = __builtin_amdgcn_mfma_f32_16x16x32_bf16(kl0, qh, s0, 0, 0, 0);
    s1 = __builtin_amdgcn_mfma_f32_16x16x32_bf16(kl1, qh, s1, 0, 0, 0);

    // ---- online softmax: common path has zero cross-lane ops ----
    const float tm = fmaxf(
        fmaxf(fmaxf(s0[0], s0[1]), fmaxf(s0[2], s0[3])),
        fmaxf(fmaxf(s1[0], s1[1]), fmaxf(s1[2], s1[3])));
    if (__any(tm > mx + 8.0f)) {   // rare (first tile + big jumps only)
      float tr = fmaxf(tm, __shfl_xor(tm, 16));
      tr = fmaxf(tr, __shfl_xor(tr, 32));
      const float mxn = fmaxf(mx, tr);
      const float corr = __expf(mx - mxn);
      ls *= corr;
      const float c0 = __shfl(corr, (g << 2) + 0);
      const float c1 = __shfl(corr, (g << 2) + 1);
      const float c2 = __shfl(corr, (g << 2) + 2);
      const float c3 = __shfl(corr, (g << 2) + 3);
      acc0[0] *= c0; acc0[1] *= c1; acc0[2] *= c2; acc0[3] *= c3;
      acc1[0] *= c0; acc1[1] *= c1; acc1[2] *= c2; acc1[3] *= c3;
      acc2[0] *= c0; acc2[1] *= c1; acc2[2] *= c2; acc2[3] *= c3;
      acc3[0] *= c0; acc3[1] *= c1; acc3[2] *= c2; acc3[3] *= c3;
      mx = mxn;
    }
    float pj[8];
    pj[0] = __expf(s0[0] - mx); pj[1] = __expf(s0[1] - mx);
    pj[2] = __expf(s0[2] - mx); pj[3] = __expf(s0[3] - mx);
    pj[4] = __expf(s1[0] - mx); pj[5] = __expf(s1[1] - mx);
    pj[6] = __expf(s1[2] - mx); pj[7] = __expf(s1[3] - mx);
    ls += ((pj[0] + pj[1]) + (pj[2] + pj[3])) + ((pj[4] + pj[5]) + (pj[6] + pj[7]));

    union { unsigned int u[4]; bf16x8 v; } pu;
    #pragma unroll
    for (int jj = 0; jj < 4; ++jj) {
      unsigned int r;
      asm("v_cvt_pk_bf16_f32 %0, %1, %2" : "=v"(r) : "v"(pj[2 * jj]), "v"(pj[2 * jj + 1]));
      pu.u[jj] = r;
    }
    // ---- PV ----
    acc0 = __builtin_amdgcn_mfma_f32_16x16x32_bf16(pu.v, v0, acc0, 0, 0, 0);
    acc1 = __builtin_amdgcn_mfma_f32_16x16x32_bf16(pu.v, v1, acc1, 0, 0, 0);
    acc2 = __builtin_amdgcn_mfma_f32_16x16x32_bf16(pu.v, v2, acc2, 0, 0, 0);
    acc3 = __builtin_amdgcn_mfma_f32_16x16x32_bf16(pu.v, v3, acc3, 0, 0, 0);
  }
  #undef STAGE

  // ---- finalize: ls row-total across g, write un-normalized partials ----
  ls += __shfl_xor(ls, 16);
  ls += __shfl_xor(ls, 32);

  const size_t mt = (size_t)blockIdx.x * 4 + w;
  ushort* Ob = Om + (mt * SPLIT + spl) * 1024;
  float*  Sb = Sm + (mt * SPLIT + spl) * 32;
  #pragma unroll
  for (int ct = 0; ct < 4; ++ct) {
    const f32x4 a = (ct == 0) ? acc0 : (ct == 1) ? acc1 : (ct == 2) ? acc2 : acc3;
    unsigned int r0, r1;
    asm("v_cvt_pk_bf16_f32 %0, %1, %2" : "=v"(r0) : "v"(a[0]), "v"(a[1]));
    asm("v_cvt_pk_bf16_f32 %0, %1, %2" : "=v"(r1) : "v"(a[2]), "v"(a[3]));
    u32x2 pk; pk[0] = r0; pk[1] = r1;
    *(u32x2*)(Ob + (ct * 16 + mloc) * 16 + 4 * g) = pk;  // e = c*16 + (4g+i)
  }
  if (l < 16) { Sb[l] = mx; Sb[16 + l] = ls; }
}

// ---------------- Kernel 3: combine split partials ---------------------------
__global__ __launch_bounds__(256) void combine_kernel(
    const ushort* __restrict__ Om, const float* __restrict__ Sm,
    const float* __restrict__ x, const float* __restrict__ gammap,
    float* __restrict__ out) {
  const int mt = blockIdx.x;
  const int m0 = mt * 16;
  const float gamma = gammap[0];
  const float* Sb = Sm + (size_t)mt * SPLIT * 32;
  const ushort* Ob = Om + (size_t)mt * SPLIT * 1024;
  for (int e = threadIdx.x; e < 1024; e += 256) {
    const int m = e & 15, c = e >> 4;
    float M = -INFINITY;
    #pragma unroll
    for (int s = 0; s < SPLIT; ++s) M = fmaxf(M, Sb[s * 32 + m]);
    float L = 0.f, val = 0.f;
    #pragma unroll
    for (int s = 0; s < SPLIT; ++s) {
      const float wgt = __expf(Sb[s * 32 + m] - M);
      L += Sb[s * 32 + 16 + m] * wgt;
      union { unsigned int i; float f; } cv;
      cv.i = ((unsigned int)Ob[s * 1024 + e]) << 16;
      val += cv.f * wgt;
    }
    const int idx = c * NPIX + m0 + m;
    out[idx] = gamma * (val / L) + x[idx];
  }
}

// ---------------- launcher ---------------------------------------------------
extern "C" void kernel_launch(void* const* d_in, const int* in_sizes, int n_in,
                              void* d_out, int out_size, void* d_ws, size_t ws_size,
                              hipStream_t stream) {
  const float* x     = (const float*)d_in[0];
  const float* Wf    = (const float*)d_in[1];
  const float* bf    = (const float*)d_in[2];
  const float* Wg    = (const float*)d_in[3];
  const float* bg    = (const float*)d_in[4];
  const float* Wh    = (const float*)d_in[5];
  const float* bh    = (const float*)d_in[6];
  const float* gamma = (const float*)d_in[7];
  const float* uf    = (const float*)d_in[8];
  const float* ug    = (const float*)d_in[9];
  const float* uh    = (const float*)d_in[10];
  float* out = (float*)d_out;

  char* ws = (char*)d_ws;
  ushort* Qp  = (ushort*)(ws + 256);                                 // 294912 B
  ushort* Kp  = (ushort*)(ws + 256 + NPIX * 16 * 2);                 // 294912 B
  ushort* Vt2 = (ushort*)(ws + 256 + 2 * NPIX * 16 * 2);             // 1179648 B
  size_t off = 256 + (size_t)2 * NPIX * 16 * 2 + (size_t)NPIX * 64 * 2;
  ushort* Om = (ushort*)(ws + off);                                  // 9437184 B
  float*  Sm = (float*)(ws + off + (size_t)MTILES * SPLIT * 1024 * 2); // 589824 B

  fgh_kernel<<<dim3(NPIX / 256, 5), 256, 0, stream>>>(x, Wf, bf, Wg, bg, Wh, bh,
                                                      uf, ug, uh, Qp, Kp, Vt2);
  attn_kernel<<<dim3(NPIX / 64, SPLIT), 256, 0, stream>>>(Qp, Kp, Vt2, Om, Sm);
  combine_kernel<<<MTILES, 256, 0, stream>>>(Om, Sm, x, gamma, out);
}